// Round 2
// baseline (1215.458 us; speedup 1.0000x reference)
//
#include <hip/hip_runtime.h>
#include <stdint.h>

#define TT 64
#define BB 1024
#define II 512
#define HH 300
#define OO 256
#define HPAD 304   // padded hidden stride (16B-aligned rows)

// ---------------------------------------------------------------------------
// helpers
// ---------------------------------------------------------------------------
__device__ __forceinline__ unsigned long long rfl64(unsigned long long v) {
    unsigned int lo = __builtin_amdgcn_readfirstlane((unsigned int)(v & 0xffffffffull));
    unsigned int hi = __builtin_amdgcn_readfirstlane((unsigned int)(v >> 32));
    return ((unsigned long long)hi << 32) | (unsigned long long)lo;
}

// ---------------------------------------------------------------------------
// Kernel 0: transpose W2 [256][300] -> W2T [300][256] (tiny, L2-resident)
// ---------------------------------------------------------------------------
__global__ void k_w2t(const float* __restrict__ W2, float* __restrict__ W2T) {
    int o = blockIdx.x;
    for (int h = threadIdx.x; h < HH; h += blockDim.x)
        W2T[h * OO + o] = W2[o * HH + h];
}

// ---------------------------------------------------------------------------
// Kernel 1: GEMM1 over ALL timesteps at once.
//   cur1[t][b][h] = x[b][t][:] . W1[h][:] + b1[h]
//   M = B*T = 65536 (row m -> b = m>>6, t = m&63), K = 512, N = 300 (5x64 pad)
//   f32 vector GEMM: 128x64 block tile, BK=32, 256 threads, 8x4 per thread.
// ---------------------------------------------------------------------------
__global__ __launch_bounds__(256) void k_gemm1(
    const float* __restrict__ x, const float* __restrict__ W1,
    const float* __restrict__ b1, float* __restrict__ cur1)
{
    // As stride 132: 132*4=528 B keeps float4 alignment; breaks pow2 bank stride
    __shared__ float As[32][132];
    __shared__ float Bs[32][68];
    const int tid = threadIdx.x;
    const int m0 = blockIdx.x * 128;
    const int n0 = blockIdx.y * 64;
    const int tm = tid >> 4;   // 0..15 -> rows tm*8..+7
    const int tn = tid & 15;   // 0..15 -> cols tn*4..+3

    float acc[8][4];
    #pragma unroll
    for (int i = 0; i < 8; i++)
        #pragma unroll
        for (int j = 0; j < 4; j++) acc[i][j] = 0.f;

    for (int k0 = 0; k0 < II; k0 += 32) {
        // stage A tile 128x32 (transposed to [k][m])
        #pragma unroll
        for (int j = 0; j < 4; j++) {
            int s = j * 256 + tid;
            int m = s >> 3, kq = s & 7;
            float4 v = *reinterpret_cast<const float4*>(
                &x[(size_t)(m0 + m) * II + k0 + kq * 4]);
            As[kq * 4 + 0][m] = v.x;
            As[kq * 4 + 1][m] = v.y;
            As[kq * 4 + 2][m] = v.z;
            As[kq * 4 + 3][m] = v.w;
        }
        // stage B tile 64x32 from W1 rows h (transposed to [k][h]); zero-pad h>=300
        #pragma unroll
        for (int j = 0; j < 2; j++) {
            int s = j * 256 + tid;
            int h = s >> 3, kq = s & 7;
            int hg = n0 + h;
            float4 v = make_float4(0.f, 0.f, 0.f, 0.f);
            if (hg < HH)
                v = *reinterpret_cast<const float4*>(&W1[(size_t)hg * II + k0 + kq * 4]);
            Bs[kq * 4 + 0][h] = v.x;
            Bs[kq * 4 + 1][h] = v.y;
            Bs[kq * 4 + 2][h] = v.z;
            Bs[kq * 4 + 3][h] = v.w;
        }
        __syncthreads();
        #pragma unroll
        for (int k = 0; k < 32; k++) {
            float a[8], b[4];
            *reinterpret_cast<float4*>(&a[0]) = *reinterpret_cast<const float4*>(&As[k][tm * 8]);
            *reinterpret_cast<float4*>(&a[4]) = *reinterpret_cast<const float4*>(&As[k][tm * 8 + 4]);
            *reinterpret_cast<float4*>(&b[0]) = *reinterpret_cast<const float4*>(&Bs[k][tn * 4]);
            #pragma unroll
            for (int i = 0; i < 8; i++)
                #pragma unroll
                for (int j = 0; j < 4; j++)
                    acc[i][j] = fmaf(a[i], b[j], acc[i][j]);
        }
        __syncthreads();
    }
    // epilogue: scatter to cur1[t][b][h] (+bias), h guard for last column block
    #pragma unroll
    for (int i = 0; i < 8; i++) {
        const int M = m0 + tm * 8 + i;
        const int b_ = M >> 6, t = M & 63;
        float* dst = cur1 + ((size_t)t * BB + b_) * HPAD + n0 + tn * 4;
        #pragma unroll
        for (int j = 0; j < 4; j++) {
            int h = n0 + tn * 4 + j;
            if (h < HH) dst[j] = acc[i][j] + b1[h];
        }
    }
}

// ---------------------------------------------------------------------------
// Kernel 2: persistent recurrence. Block = 512 threads (8 waves), owns 4 batch
// rows for all 64 steps. Grid = 256 blocks (1024/4).
//   Phase A: waves 0-3 (one per row) do LIF1 on cur1, spike masks via ballot.
//   Phase B: thread (q = tid>>8, o = tid&255); W2T rows for its h-half held in
//            150 VGPRs; masked column-sum with scalar-branch skip.
//   Phase C: q==0 half reduces partials, does LIF2, writes both outputs.
// reset_t == spk_{t-1} exactly (mem>1 vs mem-1>0 are the same predicate).
// ---------------------------------------------------------------------------
__global__ __launch_bounds__(512, 2) void k_recur(
    const float* __restrict__ cur1, const float* __restrict__ W2T,
    const float* __restrict__ b2, const float* __restrict__ beta2,
    float* __restrict__ out)
{
    const int tid  = threadIdx.x;
    const int lane = tid & 63;
    const int wid  = tid >> 6;
    const int q    = tid >> 8;    // h-half: 0 -> h<150, 1 -> h>=150
    const int o    = tid & 255;
    const int b0   = blockIdx.x * 4;

    __shared__ unsigned long long mlds[4][5];
    __shared__ float part[4][256];

    // W2T half-panel in registers: 150 f32 per thread (static indexing only)
    float w2reg[150];
    #pragma unroll
    for (int hh = 0; hh < 150; hh++)
        w2reg[hh] = W2T[(size_t)(q * 150 + hh) * OO + o];

    const float b2o = b2[o];
    const float bt2 = beta2[o];

    float m1[5], s1[5];
    #pragma unroll
    for (int p = 0; p < 5; p++) { m1[p] = 0.f; s1[p] = 0.f; }
    float m2r[4], s2r[4];
    #pragma unroll
    for (int r = 0; r < 4; r++) { m2r[r] = 0.f; s2r[r] = 0.f; }

    float* outspk = out;
    float* outmem = out + (size_t)BB * TT * OO;

    #pragma unroll 1
    for (int t = 0; t < TT; t++) {
        // ---- Phase A: LIF1 (wave w handles row b0+w; lane <-> h within pass p)
        if (wid < 4) {
            const float* crow = cur1 + ((size_t)t * BB + (b0 + wid)) * HPAD;
            #pragma unroll
            for (int p = 0; p < 5; p++) {
                int h = p * 64 + lane;
                float cur = 0.f;
                if (h < HH) cur = crow[h];
                float mnew = fmaf(0.9f, m1[p], cur) - s1[p];   // reset = prev spike
                bool s = (h < HH) && (mnew > 1.0f);
                unsigned long long bal = __ballot(s);
                m1[p] = mnew;
                s1[p] = s ? 1.0f : 0.f;
                if (lane == 0) mlds[wid][p] = bal;
            }
        }
        __syncthreads();

        // ---- Phase B: cur2 partial = sum over spiking h (this thread's half)
        unsigned long long nw[4][3];
        #pragma unroll
        for (int r = 0; r < 4; r++) {
            unsigned long long w0 = rfl64(mlds[r][0]);
            unsigned long long w1 = rfl64(mlds[r][1]);
            unsigned long long w2_ = rfl64(mlds[r][2]);
            unsigned long long w3 = rfl64(mlds[r][3]);
            unsigned long long w4 = rfl64(mlds[r][4]);
            if (q == 0) {   // window h in [0,150): bits 0..149
                nw[r][0] = w0;
                nw[r][1] = w1;
                nw[r][2] = w2_ & ((1ull << 22) - 1);
            } else {        // window h in [150,300): shift right by 150
                nw[r][0] = (w2_ >> 22) | (w3 << 42);
                nw[r][1] = (w3 >> 22) | (w4 << 42);
                nw[r][2] = (w4 >> 22);
            }
        }
        unsigned long long anyw[3];
        #pragma unroll
        for (int w = 0; w < 3; w++)
            anyw[w] = nw[0][w] | nw[1][w] | nw[2][w] | nw[3][w];

        float ac0 = (q == 0) ? b2o : 0.f;
        float ac1 = (q == 0) ? b2o : 0.f;
        float ac2 = (q == 0) ? b2o : 0.f;
        float ac3 = (q == 0) ? b2o : 0.f;
        #pragma unroll
        for (int hh = 0; hh < 150; hh++) {
            const int wd = hh >> 6;
            const unsigned long long bitm = 1ull << (hh & 63);
            if (anyw[wd] & bitm) {       // scalar branch, wave-uniform
                const float wv = w2reg[hh];
                if (nw[0][wd] & bitm) ac0 += wv;
                if (nw[1][wd] & bitm) ac1 += wv;
                if (nw[2][wd] & bitm) ac2 += wv;
                if (nw[3][wd] & bitm) ac3 += wv;
            }
        }

        if (q == 1) {
            part[0][o] = ac0; part[1][o] = ac1; part[2][o] = ac2; part[3][o] = ac3;
        }
        __syncthreads();

        // ---- Phase C: LIF2 + output stores (q==0 half only)
        if (q == 0) {
            float accv[4] = { ac0 + part[0][o], ac1 + part[1][o],
                              ac2 + part[2][o], ac3 + part[3][o] };
            #pragma unroll
            for (int r = 0; r < 4; r++) {
                float mnew = fmaf(bt2, m2r[r], accv[r]) - s2r[r];
                bool s = mnew > 1.0f;
                float sf = s ? 1.0f : 0.f;
                m2r[r] = mnew;
                s2r[r] = sf;
                outspk[((size_t)(b0 + r) * TT + t) * OO + o] = sf;
                outmem[((size_t)t * BB + (b0 + r)) * OO + o] = mnew;
            }
        }
    }
}

// ---------------------------------------------------------------------------
extern "C" void kernel_launch(void* const* d_in, const int* in_sizes, int n_in,
                              void* d_out, int out_size, void* d_ws, size_t ws_size,
                              hipStream_t stream)
{
    const float* x     = (const float*)d_in[0];
    const float* W1    = (const float*)d_in[1];
    const float* b1    = (const float*)d_in[2];
    const float* W2    = (const float*)d_in[3];
    const float* b2    = (const float*)d_in[4];
    const float* beta2 = (const float*)d_in[5];
    float* out = (float*)d_out;

    // ws layout: cur1 [64][1024][304] f32 (79,691,776 B), then W2T [300][256]
    float* cur1 = (float*)d_ws;
    float* W2T  = (float*)((char*)d_ws + (size_t)TT * BB * HPAD * 4);

    k_w2t<<<256, 256, 0, stream>>>(W2, W2T);
    k_gemm1<<<dim3(512, 5), 256, 0, stream>>>(x, W1, b1, cur1);
    k_recur<<<256, 512, 0, stream>>>(cur1, W2T, b2, beta2, out);
}

// Round 4
// 1021.784 us; speedup vs baseline: 1.1895x; 1.1895x over previous
//
#include <hip/hip_runtime.h>
#include <stdint.h>

#define TT 64
#define BB 1024
#define II 512
#define HH 300
#define OO 256
#define HPAD 304   // padded hidden stride (16B-aligned rows)

// ---------------------------------------------------------------------------
// helpers
// ---------------------------------------------------------------------------
__device__ __forceinline__ unsigned long long rfl64(unsigned long long v) {
    unsigned int lo = __builtin_amdgcn_readfirstlane((unsigned int)(v & 0xffffffffull));
    unsigned int hi = __builtin_amdgcn_readfirstlane((unsigned int)(v >> 32));
    return ((unsigned long long)hi << 32) | (unsigned long long)lo;
}

// ---------------------------------------------------------------------------
// Kernel 0: transpose W2 [256][300] -> W2T [300][256] (tiny, L2-resident)
// ---------------------------------------------------------------------------
__global__ void k_w2t(const float* __restrict__ W2, float* __restrict__ W2T) {
    int o = blockIdx.x;
    for (int h = threadIdx.x; h < HH; h += blockDim.x)
        W2T[h * OO + o] = W2[o * HH + h];
}

// ---------------------------------------------------------------------------
// Kernel 1: GEMM1 over ALL timesteps at once. (unchanged from Round 2 — passed)
//   cur1[t][b][h] = x[b][t][:] . W1[h][:] + b1[h]
// ---------------------------------------------------------------------------
__global__ __launch_bounds__(256) void k_gemm1(
    const float* __restrict__ x, const float* __restrict__ W1,
    const float* __restrict__ b1, float* __restrict__ cur1)
{
    __shared__ float As[32][132];
    __shared__ float Bs[32][68];
    const int tid = threadIdx.x;
    const int m0 = blockIdx.x * 128;
    const int n0 = blockIdx.y * 64;
    const int tm = tid >> 4;
    const int tn = tid & 15;

    float acc[8][4];
    #pragma unroll
    for (int i = 0; i < 8; i++)
        #pragma unroll
        for (int j = 0; j < 4; j++) acc[i][j] = 0.f;

    for (int k0 = 0; k0 < II; k0 += 32) {
        #pragma unroll
        for (int j = 0; j < 4; j++) {
            int s = j * 256 + tid;
            int m = s >> 3, kq = s & 7;
            float4 v = *reinterpret_cast<const float4*>(
                &x[(size_t)(m0 + m) * II + k0 + kq * 4]);
            As[kq * 4 + 0][m] = v.x;
            As[kq * 4 + 1][m] = v.y;
            As[kq * 4 + 2][m] = v.z;
            As[kq * 4 + 3][m] = v.w;
        }
        #pragma unroll
        for (int j = 0; j < 2; j++) {
            int s = j * 256 + tid;
            int h = s >> 3, kq = s & 7;
            int hg = n0 + h;
            float4 v = make_float4(0.f, 0.f, 0.f, 0.f);
            if (hg < HH)
                v = *reinterpret_cast<const float4*>(&W1[(size_t)hg * II + k0 + kq * 4]);
            Bs[kq * 4 + 0][h] = v.x;
            Bs[kq * 4 + 1][h] = v.y;
            Bs[kq * 4 + 2][h] = v.z;
            Bs[kq * 4 + 3][h] = v.w;
        }
        __syncthreads();
        #pragma unroll
        for (int k = 0; k < 32; k++) {
            float a[8], b[4];
            *reinterpret_cast<float4*>(&a[0]) = *reinterpret_cast<const float4*>(&As[k][tm * 8]);
            *reinterpret_cast<float4*>(&a[4]) = *reinterpret_cast<const float4*>(&As[k][tm * 8 + 4]);
            *reinterpret_cast<float4*>(&b[0]) = *reinterpret_cast<const float4*>(&Bs[k][tn * 4]);
            #pragma unroll
            for (int i = 0; i < 8; i++)
                #pragma unroll
                for (int j = 0; j < 4; j++)
                    acc[i][j] = fmaf(a[i], b[j], acc[i][j]);
        }
        __syncthreads();
    }
    #pragma unroll
    for (int i = 0; i < 8; i++) {
        const int M = m0 + tm * 8 + i;
        const int b_ = M >> 6, t = M & 63;
        float* dst = cur1 + ((size_t)t * BB + b_) * HPAD + n0 + tn * 4;
        #pragma unroll
        for (int j = 0; j < 4; j++) {
            int h = n0 + tn * 4 + j;
            if (h < HH) dst[j] = acc[i][j] + b1[h];
        }
    }
}

// ---------------------------------------------------------------------------
// Kernel 2: persistent recurrence, NO-SPILL version.
//   Block = 1024 threads (16 waves), grid = 256; each block owns 4 batch rows.
//   h is split in QUARTERS (q = tid>>8): w2reg[75] -> fits the 128-VGPR cap a
//   1024-thread block requires (Round-2's w2reg[150] spilled: +78 MB scratch
//   stores seen in WRITE_SIZE, latency-bound hh loop).
//   Phase A: LIF1 spread over all 16 waves. Unit u = r*5+p (20 units): wave w
//            handles u=w, and waves 0-3 also u=w+16. cur1 for t+1 prefetched.
//   Phase B: 75-bit spike-mask window (SGPR funnel shift), branchy masked sum
//            of register-resident W2T quarter.
//   Phase C: q==0 reduces 4 partials via LDS, LIF2, stores both outputs.
// reset_t == spk_{t-1} exactly (mem>1 vs mem-1>0 same predicate).
// ---------------------------------------------------------------------------
__global__ __launch_bounds__(1024, 4) void k_recur(
    const float* __restrict__ cur1, const float* __restrict__ W2T,
    const float* __restrict__ b2, const float* __restrict__ beta2,
    float* __restrict__ out)
{
    const int tid  = threadIdx.x;
    const int lane = tid & 63;
    const int wid  = tid >> 6;    // 0..15
    const int q    = tid >> 8;    // h-quarter 0..3
    const int o    = tid & 255;
    const int b0   = blockIdx.x * 4;

    __shared__ unsigned long long mlds[4][5];
    __shared__ float part[4][3][256];

    // LIF1 unit mapping
    const int u1 = wid;                  // always valid (0..15)
    const int r1 = u1 / 5, p1 = u1 - 5 * r1;
    const int u2 = wid + 16;             // valid for wid<4 (16..19)
    const int r2 = u2 / 5, p2 = u2 - 5 * r2;
    const int h1 = p1 * 64 + lane;
    const int h2 = p2 * 64 + lane;
    const bool va = (h1 < HH);
    const bool vb = (wid < 4) && (h2 < HH);

    // register-resident quarter of W2T: 75 f32 (static indexing only)
    float w2reg[75];
    #pragma unroll
    for (int i = 0; i < 75; i++)
        w2reg[i] = W2T[(size_t)(q * 75 + i) * OO + o];

    const float b2o = b2[o];
    const float bt2 = beta2[o];

    float m1a = 0.f, s1a = 0.f, m1b = 0.f, s1b = 0.f;
    float m2r[4] = {0.f, 0.f, 0.f, 0.f};
    float s2r[4] = {0.f, 0.f, 0.f, 0.f};

    const float* c1p = cur1 + (size_t)(b0 + r1) * HPAD + h1;
    const float* c2p = cur1 + (size_t)(b0 + (vb ? r2 : 0)) * HPAD + (vb ? h2 : 0);
    float c1 = va ? c1p[0] : 0.f;
    float c2 = vb ? c2p[0] : 0.f;

    float* outspk = out;
    float* outmem = out + (size_t)BB * TT * OO;

    #pragma unroll 1
    for (int t = 0; t < TT; t++) {
        // ---- Phase A: LIF1, all 16 waves
        {
            float mnew = fmaf(0.9f, m1a, c1) - s1a;
            bool s = va && (mnew > 1.0f);
            unsigned long long bal = __ballot(s);
            m1a = mnew; s1a = s ? 1.0f : 0.f;
            if (lane == 0) mlds[r1][p1] = bal;
        }
        if (wid < 4) {
            float mnew = fmaf(0.9f, m1b, c2) - s1b;
            bool s = vb && (mnew > 1.0f);
            unsigned long long bal = __ballot(s);
            m1b = mnew; s1b = s ? 1.0f : 0.f;
            if (lane == 0) mlds[r2][p2] = bal;
        }
        // prefetch cur1 for t+1 (hides HBM latency under Phase B)
        if (t + 1 < TT) {
            const size_t off = (size_t)(t + 1) * BB * HPAD;
            c1 = va ? c1p[off] : 0.f;
            c2 = vb ? c2p[off] : 0.f;
        }
        __syncthreads();

        // ---- Phase B: extract this quarter's 75-bit window per row (SGPR)
        unsigned long long nw[4][2];
        #pragma unroll
        for (int r = 0; r < 4; r++) {
            unsigned long long w0 = rfl64(mlds[r][0]);
            unsigned long long w1 = rfl64(mlds[r][1]);
            unsigned long long w2_ = rfl64(mlds[r][2]);
            unsigned long long w3 = rfl64(mlds[r][3]);
            unsigned long long w4 = rfl64(mlds[r][4]);
            if (q == 0)      { nw[r][0] = w0;                      nw[r][1] = w1; }
            else if (q == 1) { nw[r][0] = (w1 >> 11) | (w2_ << 53); nw[r][1] = (w2_ >> 11) | (w3 << 53); }
            else if (q == 2) { nw[r][0] = (w2_ >> 22) | (w3 << 42); nw[r][1] = (w3 >> 22) | (w4 << 42); }
            else             { nw[r][0] = (w3 >> 33) | (w4 << 31);  nw[r][1] = (w4 >> 33); }
        }
        unsigned long long anyw[2];
        anyw[0] = nw[0][0] | nw[1][0] | nw[2][0] | nw[3][0];
        anyw[1] = nw[0][1] | nw[1][1] | nw[2][1] | nw[3][1];

        float ac0 = (q == 0) ? b2o : 0.f;
        float ac1 = (q == 0) ? b2o : 0.f;
        float ac2 = (q == 0) ? b2o : 0.f;
        float ac3 = (q == 0) ? b2o : 0.f;
        #pragma unroll
        for (int hh = 0; hh < 75; hh++) {
            const int wd = hh >> 6;
            const unsigned long long bitm = 1ull << (hh & 63);
            if (anyw[wd] & bitm) {       // wave-uniform scalar branch
                const float wv = w2reg[hh];
                if (nw[0][wd] & bitm) ac0 += wv;
                if (nw[1][wd] & bitm) ac1 += wv;
                if (nw[2][wd] & bitm) ac2 += wv;
                if (nw[3][wd] & bitm) ac3 += wv;
            }
        }

        if (q != 0) {
            part[0][q - 1][o] = ac0;
            part[1][q - 1][o] = ac1;
            part[2][q - 1][o] = ac2;
            part[3][q - 1][o] = ac3;
        }
        __syncthreads();

        // ---- Phase C: LIF2 + output stores (q==0 threads = waves 0-3)
        if (q == 0) {
            float accv[4] = {
                ac0 + part[0][0][o] + part[0][1][o] + part[0][2][o],
                ac1 + part[1][0][o] + part[1][1][o] + part[1][2][o],
                ac2 + part[2][0][o] + part[2][1][o] + part[2][2][o],
                ac3 + part[3][0][o] + part[3][1][o] + part[3][2][o]
            };
            #pragma unroll
            for (int r = 0; r < 4; r++) {
                float mnew = fmaf(bt2, m2r[r], accv[r]) - s2r[r];
                bool s = mnew > 1.0f;
                float sf = s ? 1.0f : 0.f;
                m2r[r] = mnew;
                s2r[r] = sf;
                outspk[((size_t)(b0 + r) * TT + t) * OO + o] = sf;
                outmem[((size_t)t * BB + (b0 + r)) * OO + o] = mnew;
            }
        }
    }
}

// ---------------------------------------------------------------------------
extern "C" void kernel_launch(void* const* d_in, const int* in_sizes, int n_in,
                              void* d_out, int out_size, void* d_ws, size_t ws_size,
                              hipStream_t stream)
{
    const float* x     = (const float*)d_in[0];
    const float* W1    = (const float*)d_in[1];
    const float* b1    = (const float*)d_in[2];
    const float* W2    = (const float*)d_in[3];
    const float* b2    = (const float*)d_in[4];
    const float* beta2 = (const float*)d_in[5];
    float* out = (float*)d_out;

    // ws layout: cur1 [64][1024][304] f32 (79,691,776 B), then W2T [300][256]
    float* cur1 = (float*)d_ws;
    float* W2T  = (float*)((char*)d_ws + (size_t)TT * BB * HPAD * 4);

    k_w2t<<<256, 256, 0, stream>>>(W2, W2T);
    k_gemm1<<<dim3(512, 5), 256, 0, stream>>>(x, W1, b1, cur1);
    k_recur<<<256, 1024, 0, stream>>>(cur1, W2T, b2, beta2, out);
}

// Round 10
// 590.629 us; speedup vs baseline: 2.0579x; 1.7300x over previous
//
#include <hip/hip_runtime.h>
#include <stdint.h>

#define TT 64
#define BB 1024
#define II 512
#define HH 300
#define OO 256
#define HPAD 304   // padded hidden stride for cur1 rows
#define KP2 320    // padded K for GEMM2 (10 chunks of 32)

typedef __attribute__((ext_vector_type(8))) short bf16x8;
typedef __attribute__((ext_vector_type(4))) float f32x4;

// ---------------------------------------------------------------------------
// Kernel 1: GEMM1 over ALL timesteps (unchanged from Round 2/4 — known good).
//   cur1[t][b][h] = x[b][t][:] . W1[h][:] + b1[h]
// ---------------------------------------------------------------------------
__global__ __launch_bounds__(256) void k_gemm1(
    const float* __restrict__ x, const float* __restrict__ W1,
    const float* __restrict__ b1, float* __restrict__ cur1)
{
    __shared__ float As[32][132];
    __shared__ float Bs[32][68];
    const int tid = threadIdx.x;
    const int m0 = blockIdx.x * 128;
    const int n0 = blockIdx.y * 64;
    const int tm = tid >> 4;
    const int tn = tid & 15;

    float acc[8][4];
    #pragma unroll
    for (int i = 0; i < 8; i++)
        #pragma unroll
        for (int j = 0; j < 4; j++) acc[i][j] = 0.f;

    for (int k0 = 0; k0 < II; k0 += 32) {
        #pragma unroll
        for (int j = 0; j < 4; j++) {
            int s = j * 256 + tid;
            int m = s >> 3, kq = s & 7;
            float4 v = *reinterpret_cast<const float4*>(
                &x[(size_t)(m0 + m) * II + k0 + kq * 4]);
            As[kq * 4 + 0][m] = v.x;
            As[kq * 4 + 1][m] = v.y;
            As[kq * 4 + 2][m] = v.z;
            As[kq * 4 + 3][m] = v.w;
        }
        #pragma unroll
        for (int j = 0; j < 2; j++) {
            int s = j * 256 + tid;
            int h = s >> 3, kq = s & 7;
            int hg = n0 + h;
            float4 v = make_float4(0.f, 0.f, 0.f, 0.f);
            if (hg < HH)
                v = *reinterpret_cast<const float4*>(&W1[(size_t)hg * II + k0 + kq * 4]);
            Bs[kq * 4 + 0][h] = v.x;
            Bs[kq * 4 + 1][h] = v.y;
            Bs[kq * 4 + 2][h] = v.z;
            Bs[kq * 4 + 3][h] = v.w;
        }
        __syncthreads();
        #pragma unroll
        for (int k = 0; k < 32; k++) {
            float a[8], b[4];
            *reinterpret_cast<float4*>(&a[0]) = *reinterpret_cast<const float4*>(&As[k][tm * 8]);
            *reinterpret_cast<float4*>(&a[4]) = *reinterpret_cast<const float4*>(&As[k][tm * 8 + 4]);
            *reinterpret_cast<float4*>(&b[0]) = *reinterpret_cast<const float4*>(&Bs[k][tn * 4]);
            #pragma unroll
            for (int i = 0; i < 8; i++)
                #pragma unroll
                for (int j = 0; j < 4; j++)
                    acc[i][j] = fmaf(a[i], b[j], acc[i][j]);
        }
        __syncthreads();
    }
    #pragma unroll
    for (int i = 0; i < 8; i++) {
        const int M = m0 + tm * 8 + i;
        const int b_ = M >> 6, t = M & 63;
        float* dst = cur1 + ((size_t)t * BB + b_) * HPAD + n0 + tn * 4;
        #pragma unroll
        for (int j = 0; j < 4; j++) {
            int h = n0 + tn * 4 + j;
            if (h < HH) dst[j] = acc[i][j] + b1[h];
        }
    }
}

// ---------------------------------------------------------------------------
// Kernel 2: LIF1 scan -> spike bitmasks (unchanged; bit-identical arithmetic
// to Round-2's passing Phase A).
// ---------------------------------------------------------------------------
__global__ __launch_bounds__(256) void k_lif1(
    const float* __restrict__ cur1, unsigned long long* __restrict__ masks)
{
    const int lane = threadIdx.x & 63;
    const int wid  = threadIdx.x >> 6;
    const int gw   = blockIdx.x * 4 + wid;     // 0..5119
    const int b    = gw / 5;
    const int p    = gw - 5 * b;
    const int h    = p * 64 + lane;
    const bool valid = (h < HH);
    const float* ptr = cur1 + (size_t)b * HPAD + h;

    float mem = 0.f, s = 0.f;
    float c = valid ? ptr[0] : 0.f;
    #pragma unroll 1
    for (int t = 0; t < TT; t++) {
        float cn = 0.f;
        if ((t + 1 < TT) && valid) cn = ptr[(size_t)(t + 1) * BB * HPAD];
        float mnew = fmaf(0.9f, mem, c) - s;    // reset = prev spike (exact)
        bool sp = valid && (mnew > 1.0f);
        unsigned long long bal = __ballot(sp);
        mem = mnew; s = sp ? 1.0f : 0.f;
        if (lane == 0) masks[((size_t)t * BB + b) * 5 + p] = bal;
        c = cn;
    }
}

// ---------------------------------------------------------------------------
// Kernel 3: one-time W2 EXACT 3-way chop-split to bf16 (hi+mid+lo == v in f32,
// bitwise: chop keeps top 8 sig bits; e1 = v-hi Sterbenz-exact with <=16 sig
// bits; e2 = e1-mid exact with <=8 sig bits -> lo chop is EXACT).
// Round-7's 2-way RNE split had |W|*2^-17 residual -> flipped an output spike.
// ---------------------------------------------------------------------------
__global__ __launch_bounds__(256) void k_w2prep(
    const float* __restrict__ W2, unsigned short* __restrict__ Wh_g,
    unsigned short* __restrict__ Wm_g, unsigned short* __restrict__ Wl_g)
{
    const int g = blockIdx.x * 256 + threadIdx.x;   // 5120 = 256 o x 20 segs
    const int o = g / 20, seg = g - 20 * o;
    const int kbase = seg * 16;
    #pragma unroll
    for (int e = 0; e < 16; e++) {
        int k = kbase + e;
        float v = (k < HH) ? W2[(size_t)o * HH + k] : 0.f;
        unsigned int u0 = __builtin_bit_cast(unsigned int, v);
        float vhi = __builtin_bit_cast(float, u0 & 0xFFFF0000u);
        float e1 = v - vhi;                    // exact
        unsigned int u1 = __builtin_bit_cast(unsigned int, e1);
        float vmid = __builtin_bit_cast(float, u1 & 0xFFFF0000u);
        float e2 = e1 - vmid;                  // exact, <=8 sig bits
        unsigned int u2 = __builtin_bit_cast(unsigned int, e2);
        const size_t idx = (size_t)o * KP2 + kbase + e;
        Wh_g[idx] = (unsigned short)(u0 >> 16);
        Wm_g[idx] = (unsigned short)(u1 >> 16);
        Wl_g[idx] = (unsigned short)(u2 >> 16);   // low 16 bits of u2 are 0
    }
}

// ---------------------------------------------------------------------------
// Kernel 4: GEMM2 via MFMA, exact-split weights (3 passes: hi, mid, lo).
// cur2[m][o] = sum_h spk1[m][h]*W2[o][h]; m = t*BB+b, K = 320, N = 256.
// A expanded from mask bits to bf16 {0,1} in LDS (exact). B fragments loaded
// DIRECTLY from global (3x160 KB, L2-resident) — LDS only 15 KB.
// Layouts (m89-verified set): A lane=row(l&15), k=(l>>4)*8+e; B lane=col,
// same k-map (permutation-robust pairing); D col=l&15, row=(l>>4)*4+r.
// ---------------------------------------------------------------------------
__global__ __launch_bounds__(512) void k_gemm2(
    const unsigned long long* __restrict__ masks,
    const unsigned short* __restrict__ Wh_g,
    const unsigned short* __restrict__ Wm_g,
    const unsigned short* __restrict__ Wl_g,
    float* __restrict__ cur2)
{
    __shared__ __align__(16) unsigned long long mlds[128][5];
    __shared__ __align__(16) unsigned short Al[128][40];   // 80 B rows

    const int tid  = threadIdx.x;
    const int m0   = blockIdx.x * 128;
    const int lane = tid & 63;
    const int wid  = tid >> 6;
    const int wm   = wid >> 2;        // 0..1 -> M offset wm*64
    const int wn   = wid & 3;         // 0..3 -> N offset wn*64
    const int lr   = lane & 15;       // row/col within fragment
    const int lk   = lane >> 4;       // k-slice 0..3

    // block's 128 mask rows: 5120 B, coalesced
    if (tid < 320)
        ((int4*)&mlds[0][0])[tid] = ((const int4*)(masks + (size_t)m0 * 5))[tid];

    f32x4 acc[4][4];
    #pragma unroll
    for (int i = 0; i < 4; i++)
        #pragma unroll
        for (int j = 0; j < 4; j++)
            acc[i][j] = (f32x4){0.f, 0.f, 0.f, 0.f};

    for (int kc = 0; kc < KP2; kc += 32) {
        __syncthreads();   // orders mask preload (kc=0) / prior compute reads
        // ---- stage A: expand 8 mask bits -> 8 bf16 (16 B) per thread
        {
            const int m = tid >> 2, j = tid & 3;
            const int kpos = kc + j * 8;
            const unsigned long long w = mlds[m][kpos >> 6];
            const unsigned int byte = (unsigned int)(w >> (kpos & 63)) & 0xFFu;
            uint4 v;
            v.x = ((byte &   1u) ? 0x3F80u : 0u) | ((byte &   2u) ? 0x3F800000u : 0u);
            v.y = ((byte &   4u) ? 0x3F80u : 0u) | ((byte &   8u) ? 0x3F800000u : 0u);
            v.z = ((byte &  16u) ? 0x3F80u : 0u) | ((byte &  32u) ? 0x3F800000u : 0u);
            v.w = ((byte &  64u) ? 0x3F80u : 0u) | ((byte & 128u) ? 0x3F800000u : 0u);
            *(uint4*)&Al[m][j * 8] = v;
        }
        __syncthreads();
        // ---- compute: A frags from LDS, B frags direct from L2
        bf16x8 a[4];
        #pragma unroll
        for (int mf = 0; mf < 4; mf++)
            a[mf] = *(const bf16x8*)&Al[wm * 64 + mf * 16 + lr][lk * 8];
        #pragma unroll
        for (int nf = 0; nf < 4; nf++) {
            const size_t off = (size_t)(wn * 64 + nf * 16 + lr) * KP2 + kc + lk * 8;
            bf16x8 bh = *(const bf16x8*)(Wh_g + off);
            bf16x8 bm = *(const bf16x8*)(Wm_g + off);
            bf16x8 bl = *(const bf16x8*)(Wl_g + off);
            #pragma unroll
            for (int mf = 0; mf < 4; mf++)
                acc[mf][nf] = __builtin_amdgcn_mfma_f32_16x16x32_bf16(a[mf], bh, acc[mf][nf], 0, 0, 0);
            #pragma unroll
            for (int mf = 0; mf < 4; mf++)
                acc[mf][nf] = __builtin_amdgcn_mfma_f32_16x16x32_bf16(a[mf], bm, acc[mf][nf], 0, 0, 0);
            #pragma unroll
            for (int mf = 0; mf < 4; mf++)
                acc[mf][nf] = __builtin_amdgcn_mfma_f32_16x16x32_bf16(a[mf], bl, acc[mf][nf], 0, 0, 0);
        }
    }
    // ---- epilogue: D lane mapping col=l&15, row=(l>>4)*4+r
    #pragma unroll
    for (int mf = 0; mf < 4; mf++)
        #pragma unroll
        for (int nf = 0; nf < 4; nf++) {
            #pragma unroll
            for (int r = 0; r < 4; r++) {
                int row = m0 + wm * 64 + mf * 16 + lk * 4 + r;
                int col = wn * 64 + nf * 16 + lr;
                cur2[(size_t)row * OO + col] = acc[mf][nf][r];
            }
        }
}

// ---------------------------------------------------------------------------
// Kernel 5: LIF2 scan + outputs (unchanged).
// ---------------------------------------------------------------------------
__global__ __launch_bounds__(256) void k_lif2(
    const float* __restrict__ cur2, const float* __restrict__ b2,
    const float* __restrict__ beta2, float* __restrict__ out)
{
    const int o = threadIdx.x;
    const int b = blockIdx.x;
    const float b2o = b2[o], bt2 = beta2[o];
    float mem = 0.f, s = 0.f;
    float* outspk = out;
    float* outmem = out + (size_t)BB * TT * OO;
    const float* src = cur2 + (size_t)b * OO + o;

    float c = src[0];
    #pragma unroll 1
    for (int t = 0; t < TT; t++) {
        float cn = (t + 1 < TT) ? src[(size_t)(t + 1) * BB * OO] : 0.f;
        float mnew = fmaf(bt2, mem, c + b2o) - s;
        bool sp = mnew > 1.0f;
        float sf = sp ? 1.0f : 0.f;
        outspk[((size_t)b * TT + t) * OO + o] = sf;
        outmem[((size_t)t * BB + b) * OO + o] = mnew;
        mem = mnew; s = sf;
        c = cn;
    }
}

// ---------------------------------------------------------------------------
extern "C" void kernel_launch(void* const* d_in, const int* in_sizes, int n_in,
                              void* d_out, int out_size, void* d_ws, size_t ws_size,
                              hipStream_t stream)
{
    const float* x     = (const float*)d_in[0];
    const float* W1    = (const float*)d_in[1];
    const float* b1    = (const float*)d_in[2];
    const float* W2    = (const float*)d_in[3];
    const float* b2    = (const float*)d_in[4];
    const float* beta2 = (const float*)d_in[5];
    float* out = (float*)d_out;

    // ws layout:
    //   [0, 79.7 MB)   cur1 [64][1024][304] f32; later overwritten by
    //                  cur2 [65536][256] f32 (67.1 MB) — gemm2 reads only masks
    //   [79.7, 82.3)   masks [65536][5] u64 (2.62 MB)
    //   [82.3, ...)    Wh_g, Wm_g, Wl_g [256][320] bf16 (160 KB each)
    char* base = (char*)d_ws;
    float* cur1 = (float*)base;
    float* cur2 = (float*)base;
    unsigned long long* masks = (unsigned long long*)(base + (size_t)TT * BB * HPAD * 4);
    unsigned short* Wh_g = (unsigned short*)(base + (size_t)TT * BB * HPAD * 4 + (size_t)TT * BB * 5 * 8);
    unsigned short* Wm_g = Wh_g + (size_t)OO * KP2;
    unsigned short* Wl_g = Wm_g + (size_t)OO * KP2;

    k_gemm1<<<dim3(512, 5), 256, 0, stream>>>(x, W1, b1, cur1);
    k_w2prep<<<20, 256, 0, stream>>>(W2, Wh_g, Wm_g, Wl_g);
    k_lif1<<<1280, 256, 0, stream>>>(cur1, masks);
    k_gemm2<<<512, 512, 0, stream>>>(masks, Wh_g, Wm_g, Wl_g, cur2);
    k_lif2<<<1024, 256, 0, stream>>>(cur2, b2, beta2, out);
}